// Round 1
// baseline (300.423 us; speedup 1.0000x reference)
//
#include <hip/hip_runtime.h>

typedef __attribute__((ext_vector_type(8))) short bf16x8;
typedef __attribute__((ext_vector_type(4))) float f32x4;
typedef __attribute__((ext_vector_type(4))) unsigned int u32x4;

#define DD 512
#define RR 64
#define BTOT 65536
#define BM 128
#define BN 128
#define BKT 64
#define NKT (DD / BKT)  // 8

static __device__ __forceinline__ unsigned short f2bf(float f) {
    union { float f; unsigned u; } v; v.f = f;
    unsigned r = v.u + 0x7fffu + ((v.u >> 16) & 1u);
    return (unsigned short)(r >> 16);
}

// pack two fp32 -> two bf16 (round-half-up) in one v_perm
static __device__ __forceinline__ unsigned pack2bf(float x, float y) {
    union { float f; unsigned u; } a, b;
    a.f = x; b.f = y;
    unsigned ax = a.u + 0x8000u, bx = b.u + 0x8000u;
    return __builtin_amdgcn_perm(bx, ax, 0x07060302u);
}

// ---- Kernel 1: normalize columns of params (D x R) -> U (R x D) fp32 ----
__global__ void normalize_kernel(const float* __restrict__ P, float* __restrict__ U) {
    int i = blockIdx.x;       // reflection index 0..63
    int t = threadIdx.x;      // 0..255
    __shared__ float red[4];
    float a = P[t * RR + i];
    float b = P[(t + 256) * RR + i];
    float p = a * a + b * b;
#pragma unroll
    for (int off = 32; off > 0; off >>= 1) p += __shfl_down(p, off);
    if ((t & 63) == 0) red[t >> 6] = p;
    __syncthreads();
    float s = red[0] + red[1] + red[2] + red[3];
    float inv = 1.0f / sqrtf(s);
    U[i * DD + t]       = a * inv;
    U[i * DD + t + 256] = b * inv;
}

// ---- Kernel 2: compose M = H0..H63, one column per wave, barrier-free ----
// Each wave holds its column in 8 VGPRs (d = 64*j + lane); dot via shfl_xor
// butterfly; next-u prefetched. Also folds the sldj passthrough copy
// (512 blocks x 64 lanes x float2 = 65536 floats) so gemm has no stray stores.
__global__ void compose_kernel(const float* __restrict__ U,
                               unsigned short* __restrict__ Mt,
                               const float* __restrict__ sldj,
                               float* __restrict__ sldj_out) {
    int c = blockIdx.x;   // column 0..511
    int l = threadIdx.x;  // 0..63 (one wave)

    ((float2*)sldj_out)[(size_t)c * 64 + l] = ((const float2*)sldj)[(size_t)c * 64 + l];

    float v[8], u[8], un[8];
#pragma unroll
    for (int j = 0; j < 8; ++j) v[j] = (64 * j + l == c) ? 1.0f : 0.0f;
#pragma unroll
    for (int j = 0; j < 8; ++j) u[j] = U[64 * j + l];

    for (int i = 0; i < RR; ++i) {
        int inext = (i + 1 < RR) ? i + 1 : i;
#pragma unroll
        for (int j = 0; j < 8; ++j) un[j] = U[inext * DD + 64 * j + l];
        // per-lane partial dot, shallow tree to cut the dependent-FMA chain
        float s0 = v[0] * u[0] + v[1] * u[1];
        float s1 = v[2] * u[2] + v[3] * u[3];
        float s2 = v[4] * u[4] + v[5] * u[5];
        float s3 = v[6] * u[6] + v[7] * u[7];
        float s = (s0 + s1) + (s2 + s3);
#pragma unroll
        for (int off = 32; off > 0; off >>= 1) s += __shfl_xor(s, off);
        s *= 2.0f;
#pragma unroll
        for (int j = 0; j < 8; ++j) v[j] -= s * u[j];
#pragma unroll
        for (int j = 0; j < 8; ++j) u[j] = un[j];
    }
#pragma unroll
    for (int j = 0; j < 8; ++j) Mt[(size_t)(64 * j + l) * DD + c] = f2bf(v[j]);
}

// ---- Kernel 3: out = x @ M ----
// 128x128 tile, BK=64, 8 K-tiles. A: global->reg->pack2bf->swizzled ds_write
// (bf16 in LDS). B: global_load_lds with inverse-swizzled global source.
// 8-slot XOR swizzle (slot ^= row&7) on 128B rows => conflict-free b128 reads.
// Raw s_barrier + counted vmcnt: next A-tile's 8 loads stay in flight across
// both barriers; s_waitcnt vmcnt(8) retires exactly this tile's 4 B-gloads.
__launch_bounds__(256, 3)
__global__ void gemm_kernel(const float* __restrict__ X,
                            const unsigned short* __restrict__ Mt,
                            float* __restrict__ out) {
    __shared__ __attribute__((aligned(16))) unsigned short lA[BM * BKT];  // 16 KB
    __shared__ __attribute__((aligned(16))) unsigned short lB[BN * BKT];  // 16 KB

    int t = threadIdx.x;
    int bid = blockIdx.x;

    // XCD-aware remap: 4 consecutive-slot blocks on one XCD share an A row-tile
    int row_t = (bid >> 5) * 8 + (bid & 7);   // 0..511
    int col_t = (bid >> 3) & 3;               // 0..3
    int row0 = row_t * BM;
    int col0 = col_t * BN;

    int wave = t >> 6, lane = t & 63;
    int wm = wave >> 1, wn = wave & 1;
    int quad = lane >> 4, l16 = lane & 15;

    // ---- A staging geometry: thread owns row t>>1, k-half (t&1)*32 ----
    int arow = t >> 1, ah = t & 1;
    const float4* aSrc = (const float4*)(X + (size_t)(row0 + arow) * DD + ah * 32);
    unsigned short* aDst0 = lA + arow * 64;   // 128B row
    int s_base = 4 * ah;                      // first of 4 slot indices
    int arx = arow & 7;

    // ---- B staging geometry: lane stages row wave*32 + q*8 + (lane>>3),
    //      slot lane&7 holds k-group (lane&7)^(row&7) -> pre-swizzled source
    int bln = lane >> 3;
    int bg = (lane & 7) ^ bln;
    const unsigned short* bSrc = Mt + (size_t)(col0 + wave * 32 + bln) * DD + bg * 8;

    // ---- compute geometry ----
    const unsigned short* aRd = lA + (wm * 64 + l16) * 64;
    const unsigned short* bRd = lB + (wn * 64 + l16) * 64;
    int so0 = (quad ^ (l16 & 7)) * 8;         // sl=0: k-group = quad
    int so1 = ((4 + quad) ^ (l16 & 7)) * 8;   // sl=1: k-group = 4+quad

    f32x4 acc[4][4] = {};

    // prologue: issue A loads for tile 0
    float4 av[8];
#pragma unroll
    for (int j = 0; j < 8; ++j) av[j] = aSrc[j];

#pragma unroll 1
    for (int kt = 0; kt < NKT; ++kt) {
        // convert + swizzled LDS-write of A tile kt (compiler waits on av)
#pragma unroll
        for (int j4 = 0; j4 < 4; ++j4) {
            u32x4 wv;
            float4 x0 = av[2 * j4], x1 = av[2 * j4 + 1];
            wv.x = pack2bf(x0.x, x0.y);
            wv.y = pack2bf(x0.z, x0.w);
            wv.z = pack2bf(x1.x, x1.y);
            wv.w = pack2bf(x1.z, x1.w);
            *(u32x4*)(aDst0 + ((s_base + j4) ^ arx) * 8) = wv;
        }
        // B tile kt via DMA (linear LDS dest, swizzle folded into source addr)
#pragma unroll
        for (int q = 0; q < 4; ++q) {
            __builtin_amdgcn_global_load_lds(
                (const __attribute__((address_space(1))) unsigned int*)(bSrc + (size_t)q * 8 * DD + kt * BKT),
                (__attribute__((address_space(3))) unsigned int*)(lB + (wave * 4 + q) * 512),
                16, 0, 0);
        }
        // pin issue order: B-gloads above, A prefetch below (vmcnt count exact)
        __builtin_amdgcn_sched_barrier(0);
        if (kt + 1 < NKT) {
            const float4* apn = aSrc + (kt + 1) * (BKT / 4);
#pragma unroll
            for (int j = 0; j < 8; ++j) av[j] = apn[j];
            // own ds_writes done + own 4 B-gloads retired; 8 A-loads stay in flight
            asm volatile("s_waitcnt vmcnt(8) lgkmcnt(0)" ::: "memory");
        } else {
            asm volatile("s_waitcnt vmcnt(0) lgkmcnt(0)" ::: "memory");
        }
        __builtin_amdgcn_s_barrier();           // all waves' staging now visible
        asm volatile("" ::: "memory");

#pragma unroll
        for (int sl = 0; sl < 2; ++sl) {
            int so = sl ? so1 : so0;
            bf16x8 af[4], bf[4];
#pragma unroll
            for (int mt = 0; mt < 4; ++mt) af[mt] = *(const bf16x8*)(aRd + mt * 1024 + so);
#pragma unroll
            for (int nt = 0; nt < 4; ++nt) bf[nt] = *(const bf16x8*)(bRd + nt * 1024 + so);
#pragma unroll
            for (int mt = 0; mt < 4; ++mt)
#pragma unroll
                for (int nt = 0; nt < 4; ++nt)
                    acc[mt][nt] = __builtin_amdgcn_mfma_f32_16x16x32_bf16(af[mt], bf[nt], acc[mt][nt], 0, 0, 0);
        }
        asm volatile("s_waitcnt lgkmcnt(0)" ::: "memory");  // own ds_reads retired
        __builtin_amdgcn_s_barrier();                        // safe to overwrite LDS
        asm volatile("" ::: "memory");
    }

    // Epilogue: C/D layout col = lane&15, row = quad*4 + r
#pragma unroll
    for (int mt = 0; mt < 4; ++mt) {
#pragma unroll
        for (int r = 0; r < 4; ++r) {
            int row = row0 + wm * 64 + mt * 16 + quad * 4 + r;
            float* orow = out + (size_t)row * DD + col0 + wn * 64 + l16;
#pragma unroll
            for (int nt = 0; nt < 4; ++nt)
                orow[nt * 16] = acc[mt][nt][r];
        }
    }
}

extern "C" void kernel_launch(void* const* d_in, const int* in_sizes, int n_in,
                              void* d_out, int out_size, void* d_ws, size_t ws_size,
                              hipStream_t stream) {
    const float* x      = (const float*)d_in[0];
    const float* sldj   = (const float*)d_in[1];
    const float* params = (const float*)d_in[2];
    float* out = (float*)d_out;

    float* U = (float*)d_ws;                                                       // 64*512 fp32 = 128 KB
    unsigned short* Mt = (unsigned short*)((char*)d_ws + RR * DD * sizeof(float)); // 512*512 bf16 = 512 KB

    normalize_kernel<<<RR, 256, 0, stream>>>(params, U);
    compose_kernel<<<DD, 64, 0, stream>>>(U, Mt, sldj, out + (size_t)BTOT * DD);
    gemm_kernel<<<(BTOT / BM) * (DD / BN), 256, 0, stream>>>(x, Mt, out);
}

// Round 2
// 287.703 us; speedup vs baseline: 1.0442x; 1.0442x over previous
//
#include <hip/hip_runtime.h>

typedef __attribute__((ext_vector_type(8))) short bf16x8;
typedef __attribute__((ext_vector_type(4))) float f32x4;
typedef __attribute__((ext_vector_type(4))) unsigned int u32x4;

#define DD 512
#define RR 64
#define BTOT 65536
#define BM 128
#define BN 128
#define BK 32
#define NKT (DD / BK)  // 16

static __device__ __forceinline__ unsigned short f2bf(float f) {
    union { float f; unsigned u; } v; v.f = f;
    unsigned r = v.u + 0x7fffu + ((v.u >> 16) & 1u);
    return (unsigned short)(r >> 16);
}

// pack two fp32 -> two bf16 (round-half-up) in one v_perm
static __device__ __forceinline__ unsigned pack2bf(float x, float y) {
    union { float f; unsigned u; } a, b;
    a.f = x; b.f = y;
    unsigned ax = a.u + 0x8000u, bx = b.u + 0x8000u;
    return __builtin_amdgcn_perm(bx, ax, 0x07060302u);
}

// ---- Kernel 1: normalize columns of params (D x R) -> U (R x D) fp32 ----
__global__ void normalize_kernel(const float* __restrict__ P, float* __restrict__ U) {
    int i = blockIdx.x;       // reflection index 0..63
    int t = threadIdx.x;      // 0..255
    __shared__ float red[4];
    float a = P[t * RR + i];
    float b = P[(t + 256) * RR + i];
    float p = a * a + b * b;
#pragma unroll
    for (int off = 32; off > 0; off >>= 1) p += __shfl_down(p, off);
    if ((t & 63) == 0) red[t >> 6] = p;
    __syncthreads();
    float s = red[0] + red[1] + red[2] + red[3];
    float inv = 1.0f / sqrtf(s);
    U[i * DD + t]       = a * inv;
    U[i * DD + t + 256] = b * inv;
}

// ---- Kernel 2: compose M = H0..H63, one column per wave, barrier-free ----
__global__ void compose_kernel(const float* __restrict__ U,
                               unsigned short* __restrict__ Mt,
                               const float* __restrict__ sldj,
                               float* __restrict__ sldj_out) {
    int c = blockIdx.x;   // column 0..511
    int l = threadIdx.x;  // 0..63 (one wave)

    ((float2*)sldj_out)[(size_t)c * 64 + l] = ((const float2*)sldj)[(size_t)c * 64 + l];

    float v[8], u[8], un[8];
#pragma unroll
    for (int j = 0; j < 8; ++j) v[j] = (64 * j + l == c) ? 1.0f : 0.0f;
#pragma unroll
    for (int j = 0; j < 8; ++j) u[j] = U[64 * j + l];

    for (int i = 0; i < RR; ++i) {
        int inext = (i + 1 < RR) ? i + 1 : i;
#pragma unroll
        for (int j = 0; j < 8; ++j) un[j] = U[inext * DD + 64 * j + l];
        float s0 = v[0] * u[0] + v[1] * u[1];
        float s1 = v[2] * u[2] + v[3] * u[3];
        float s2 = v[4] * u[4] + v[5] * u[5];
        float s3 = v[6] * u[6] + v[7] * u[7];
        float s = (s0 + s1) + (s2 + s3);
#pragma unroll
        for (int off = 32; off > 0; off >>= 1) s += __shfl_xor(s, off);
        s *= 2.0f;
#pragma unroll
        for (int j = 0; j < 8; ++j) v[j] -= s * u[j];
#pragma unroll
        for (int j = 0; j < 8; ++j) u[j] = un[j];
    }
#pragma unroll
    for (int j = 0; j < 8; ++j) Mt[(size_t)(64 * j + l) * DD + c] = f2bf(v[j]);
}

// ---- Kernel 3: out = x @ M ----
// 128x128 tile, BK=32, 16 K-steps, DOUBLE-BUFFERED LDS, one barrier per step.
// A: global->reg (issued 1 iter ahead) -> pack2bf -> swizzled ds_write.
// B: global_load_lds into back buffer (issued 1 compute-phase ahead),
//    swizzle folded into global source address (linear LDS dest).
// slot ^= row&3 swizzle on 64B rows -> conflict-free b128 reads.
// Counted vmcnt(4): retires exactly this step's 2 B-DMAs, keeps the 4
// A-prefetch loads in flight across the barrier.
__launch_bounds__(256, 4)
__global__ void gemm_kernel(const float* __restrict__ X,
                            const unsigned short* __restrict__ Mt,
                            float* __restrict__ out) {
    __shared__ __attribute__((aligned(16))) unsigned short lA2[2][BM * BK];  // 2 x 8 KB
    __shared__ __attribute__((aligned(16))) unsigned short lB2[2][BN * BK];  // 2 x 8 KB

    int t = threadIdx.x;
    int bid = blockIdx.x;

    // XCD-aware remap: 4 consecutive-slot blocks on one XCD share an A row-tile
    int row_t = (bid >> 5) * 8 + (bid & 7);   // 0..511
    int col_t = (bid >> 3) & 3;               // 0..3
    int row0 = row_t * BM;
    int col0 = col_t * BN;

    int wave = t >> 6, lane = t & 63;
    int wm = wave >> 1, wn = wave & 1;
    int quad = lane >> 4, l16 = lane & 15;

    // ---- A staging: thread owns row ar = t>>1, k-half ah = t&1 (16 floats) ----
    int ar = t >> 1, ah = t & 1;
    const float4* aSrcT = (const float4*)(X + (size_t)(row0 + ar) * DD) + ah * 4;
    int arx = ar & 3;
    int as0 = ((2 * ah) ^ arx) * 8;       // shorts offset of k-group 2h within row
    int as1 = ((2 * ah + 1) ^ arx) * 8;   // k-group 2h+1
    int aDstRow = ar * BK;                 // shorts

    // ---- B staging: wave w, issue q covers rows w*32+q*16+(lane>>2), lin slot lane&3;
    //      content k-group g = slot ^ (row&3) -> pre-swizzled source ----
    int bg = (lane & 3) ^ ((lane >> 2) & 3);
    const unsigned short* bSrc = Mt + (size_t)(col0 + wave * 32 + (lane >> 2)) * DD + bg * 8;
    int bDst = wave * 2 * 512;             // + q*512 shorts; lane offset by HW

    // ---- compute geometry: row R, k-group q at slot q^(R&3); R&3 == l16&3 ----
    int fro = (quad ^ (l16 & 3)) * 8;
    int aRdRow = (wm * 64 + l16) * BK + fro;   // mt stride 512 shorts
    int bRdRow = (wn * 64 + l16) * BK + fro;   // nt stride 512 shorts

    unsigned short* lA = &lA2[0][0];
    unsigned short* lB = &lB2[0][0];

    f32x4 acc[4][4] = {};
    float4 av[4];

    // ---- prologue: stage tile 0, prefetch A(1) ----
#pragma unroll
    for (int j = 0; j < 4; ++j) av[j] = aSrcT[j];
#pragma unroll
    for (int q = 0; q < 2; ++q)
        __builtin_amdgcn_global_load_lds(
            (const __attribute__((address_space(1))) unsigned int*)(bSrc + (size_t)q * 16 * DD),
            (__attribute__((address_space(3))) unsigned int*)(lB + bDst + q * 512),
            16, 0, 0);
    __builtin_amdgcn_sched_barrier(0);
    {
        u32x4 w0, w1;
        w0.x = pack2bf(av[0].x, av[0].y); w0.y = pack2bf(av[0].z, av[0].w);
        w0.z = pack2bf(av[1].x, av[1].y); w0.w = pack2bf(av[1].z, av[1].w);
        w1.x = pack2bf(av[2].x, av[2].y); w1.y = pack2bf(av[2].z, av[2].w);
        w1.z = pack2bf(av[3].x, av[3].y); w1.w = pack2bf(av[3].z, av[3].w);
        *(u32x4*)(lA + aDstRow + as0) = w0;
        *(u32x4*)(lA + aDstRow + as1) = w1;
    }
    __builtin_amdgcn_sched_barrier(0);
#pragma unroll
    for (int j = 0; j < 4; ++j) av[j] = aSrcT[8 + j];
    __builtin_amdgcn_sched_barrier(0);
    // outstanding: B(0):2 (oldest) + A(1):4 -> retire B(0) only
    asm volatile("s_waitcnt vmcnt(4) lgkmcnt(0)" ::: "memory");
    __builtin_amdgcn_s_barrier();
    asm volatile("" ::: "memory");

    int p = 0;
#pragma unroll 1
    for (int kt = 0; kt < NKT - 1; ++kt) {
        unsigned short* lAs = lA + (p ^ 1) * (BM * BK);
        unsigned short* lBs = lB + (p ^ 1) * (BN * BK);
        // stage A(kt+1) from av (loaded a full iteration ago)
        {
            u32x4 w0, w1;
            w0.x = pack2bf(av[0].x, av[0].y); w0.y = pack2bf(av[0].z, av[0].w);
            w0.z = pack2bf(av[1].x, av[1].y); w0.w = pack2bf(av[1].z, av[1].w);
            w1.x = pack2bf(av[2].x, av[2].y); w1.y = pack2bf(av[2].z, av[2].w);
            w1.z = pack2bf(av[3].x, av[3].y); w1.w = pack2bf(av[3].z, av[3].w);
            *(u32x4*)(lAs + aDstRow + as0) = w0;
            *(u32x4*)(lAs + aDstRow + as1) = w1;
        }
        // B DMA (kt+1) into back buffer
#pragma unroll
        for (int q = 0; q < 2; ++q)
            __builtin_amdgcn_global_load_lds(
                (const __attribute__((address_space(1))) unsigned int*)(bSrc + (size_t)q * 16 * DD + (kt + 1) * BK),
                (__attribute__((address_space(3))) unsigned int*)(lBs + bDst + q * 512),
                16, 0, 0);
        __builtin_amdgcn_sched_barrier(0);
        if (kt < NKT - 2) {
#pragma unroll
            for (int j = 0; j < 4; ++j) av[j] = aSrcT[(kt + 2) * 8 + j];
        }
        __builtin_amdgcn_sched_barrier(0);
        // compute tile kt from front buffer (B latency hides under this)
        {
            const unsigned short* lAc = lA + p * (BM * BK);
            const unsigned short* lBc = lB + p * (BN * BK);
            bf16x8 af[4], bf[4];
#pragma unroll
            for (int mt = 0; mt < 4; ++mt) af[mt] = *(const bf16x8*)(lAc + aRdRow + mt * 512);
#pragma unroll
            for (int nt = 0; nt < 4; ++nt) bf[nt] = *(const bf16x8*)(lBc + bRdRow + nt * 512);
#pragma unroll
            for (int mt = 0; mt < 4; ++mt)
#pragma unroll
                for (int nt = 0; nt < 4; ++nt)
                    acc[mt][nt] = __builtin_amdgcn_mfma_f32_16x16x32_bf16(af[mt], bf[nt], acc[mt][nt], 0, 0, 0);
        }
        // retire this step's B-DMA (2 oldest); keep 4 A-prefetch loads in flight
        if (kt < NKT - 2)
            asm volatile("s_waitcnt vmcnt(4) lgkmcnt(0)" ::: "memory");
        else
            asm volatile("s_waitcnt vmcnt(0) lgkmcnt(0)" ::: "memory");
        __builtin_amdgcn_s_barrier();
        asm volatile("" ::: "memory");
        p ^= 1;
    }
    // final tile NKT-1 from buffer p
    {
        const unsigned short* lAc = lA + p * (BM * BK);
        const unsigned short* lBc = lB + p * (BN * BK);
        bf16x8 af[4], bf[4];
#pragma unroll
        for (int mt = 0; mt < 4; ++mt) af[mt] = *(const bf16x8*)(lAc + aRdRow + mt * 512);
#pragma unroll
        for (int nt = 0; nt < 4; ++nt) bf[nt] = *(const bf16x8*)(lBc + bRdRow + nt * 512);
#pragma unroll
        for (int mt = 0; mt < 4; ++mt)
#pragma unroll
            for (int nt = 0; nt < 4; ++nt)
                acc[mt][nt] = __builtin_amdgcn_mfma_f32_16x16x32_bf16(af[mt], bf[nt], acc[mt][nt], 0, 0, 0);
    }

    // Epilogue: C/D layout col = lane&15, row = quad*4 + r
#pragma unroll
    for (int mt = 0; mt < 4; ++mt) {
#pragma unroll
        for (int r = 0; r < 4; ++r) {
            int row = row0 + wm * 64 + mt * 16 + quad * 4 + r;
            float* orow = out + (size_t)row * DD + col0 + wn * 64 + l16;
#pragma unroll
            for (int nt = 0; nt < 4; ++nt)
                orow[nt * 16] = acc[mt][nt][r];
        }
    }
}

extern "C" void kernel_launch(void* const* d_in, const int* in_sizes, int n_in,
                              void* d_out, int out_size, void* d_ws, size_t ws_size,
                              hipStream_t stream) {
    const float* x      = (const float*)d_in[0];
    const float* sldj   = (const float*)d_in[1];
    const float* params = (const float*)d_in[2];
    float* out = (float*)d_out;

    float* U = (float*)d_ws;                                                       // 64*512 fp32 = 128 KB
    unsigned short* Mt = (unsigned short*)((char*)d_ws + RR * DD * sizeof(float)); // 512*512 bf16 = 512 KB

    normalize_kernel<<<RR, 256, 0, stream>>>(params, U);
    compose_kernel<<<DD, 64, 0, stream>>>(U, Mt, sldj, out + (size_t)BTOT * DD);
    gemm_kernel<<<(BTOT / BM) * (DD / BN), 256, 0, stream>>>(x, Mt, out);
}